// Round 1
// baseline (767.361 us; speedup 1.0000x reference)
//
#include <hip/hip_runtime.h>
#include <math.h>

#define DIM 1024
#define NH 16
#define NKV 4
#define HD 64
#define HALF (HD/2)
#define NB 2
#define SEQ 2048
#define KVD (NKV*HD)      // 256
#define MTOT (NB*SEQ)     // 4096
#define NTOT (DIM+2*KVD)  // 1536

#define BM 64
#define BN 64
#define BKT 16

// ---------------- rope cos/sin table ----------------
__global__ __launch_bounds__(256) void rope_table_kernel(float* __restrict__ cosb,
                                                         float* __restrict__ sinb)
{
    int idx = blockIdx.x * 256 + threadIdx.x;
    if (idx >= SEQ * HALF) return;
    int t = idx / HALF;
    int d = idx % HALF;
    float e = (float)(2 * d) / (float)HD;
    float invf = 1.0f / powf(10000.0f, e);
    float f = (float)t * invf;
    cosb[idx] = cosf(f);
    sinb[idx] = sinf(f);
}

// ---------------- shared fp32 GEMM tile core (64x64, K-tile 16) ----------------
__device__ __forceinline__ void gemm64(const float* __restrict__ A, int lda,
                                       const float* __restrict__ B, int ldb,
                                       int m0, int n0, int K,
                                       float (&acc)[4][4],
                                       float (*As)[68], float (*Bs)[68])
{
    const int tid = threadIdx.x;
    const int tx = tid & 15, ty = tid >> 4;
    const int lm = tid >> 2;          // A tile row 0..63
    const int lk4 = (tid & 3) * 4;    // A k offset {0,4,8,12}
    const int lk = tid >> 4;          // B tile k row 0..15
    const int ln4 = (tid & 15) * 4;   // B col offset
#pragma unroll
    for (int i = 0; i < 4; i++)
#pragma unroll
        for (int j = 0; j < 4; j++) acc[i][j] = 0.0f;

    for (int k0 = 0; k0 < K; k0 += BKT) {
        float4 av = *(const float4*)&A[(size_t)(m0 + lm) * lda + k0 + lk4];
        float4 bv = *(const float4*)&B[(size_t)(k0 + lk) * ldb + n0 + ln4];
        As[lk4 + 0][lm] = av.x; As[lk4 + 1][lm] = av.y;
        As[lk4 + 2][lm] = av.z; As[lk4 + 3][lm] = av.w;
        *(float4*)&Bs[lk][ln4] = bv;
        __syncthreads();
#pragma unroll
        for (int kk = 0; kk < BKT; kk++) {
            float4 a4 = *(const float4*)&As[kk][ty * 4];
            float4 b4 = *(const float4*)&Bs[kk][tx * 4];
            float a[4] = {a4.x, a4.y, a4.z, a4.w};
            float bb[4] = {b4.x, b4.y, b4.z, b4.w};
#pragma unroll
            for (int i = 0; i < 4; i++)
#pragma unroll
                for (int j = 0; j < 4; j++)
                    acc[i][j] = fmaf(a[i], bb[j], acc[i][j]);
        }
        __syncthreads();
    }
}

// ---------------- fused QKV projection + bias + RoPE ----------------
__global__ __launch_bounds__(256) void qkv_rope_kernel(
    const float* __restrict__ x,
    const float* __restrict__ Wq, const float* __restrict__ bq,
    const float* __restrict__ Wk, const float* __restrict__ bk,
    const float* __restrict__ Wv, const float* __restrict__ bv,
    const float* __restrict__ cosb, const float* __restrict__ sinb,
    float* __restrict__ qbuf, float* __restrict__ kbuf, float* __restrict__ vbuf)
{
    __shared__ float As[BKT][68];
    __shared__ float Bs[BKT][68];
    const int n0g = blockIdx.x * BN;   // 0..1535
    const int m0 = blockIdx.y * BM;
    const float* Bp; const float* bias; int ldb; int mode; int n0;
    if (n0g < DIM)              { Bp = Wq; bias = bq; ldb = DIM; mode = 0; n0 = n0g; }
    else if (n0g < DIM + KVD)   { Bp = Wk; bias = bk; ldb = KVD; mode = 1; n0 = n0g - DIM; }
    else                        { Bp = Wv; bias = bv; ldb = KVD; mode = 2; n0 = n0g - DIM - KVD; }

    float acc[4][4];
    gemm64(x, DIM, Bp, ldb, m0, n0, DIM, acc, As, Bs);

    const int tid = threadIdx.x;
    const int tx = tid & 15, ty = tid >> 4;
    const int ncol = n0 + tx * 4;
#pragma unroll
    for (int i = 0; i < 4; i++) {
        const int m = m0 + ty * 4 + i;
        const int t = m & (SEQ - 1);
        float v0 = acc[i][0] + bias[ncol + 0];
        float v1 = acc[i][1] + bias[ncol + 1];
        float v2 = acc[i][2] + bias[ncol + 2];
        float v3 = acc[i][3] + bias[ncol + 3];
        if (mode == 2) {
            *(float4*)&vbuf[(size_t)m * KVD + ncol] = make_float4(v0, v1, v2, v3);
        } else {
            // reference rotary: out[d] = x1*cos - x2*sin ; out[d+32] = x1*sin - x2*cos
            const int hbase = ncol & ~(HD - 1);
            const int p0 = ncol & (HD - 1);   // multiple of 4
            const int d0 = p0 >> 1;           // even, pairs (d0, d0+1)
            float c0v = cosb[t * HALF + d0],     s0v = sinb[t * HALF + d0];
            float c1v = cosb[t * HALF + d0 + 1], s1v = sinb[t * HALF + d0 + 1];
            float* dst = (mode == 0) ? &qbuf[(size_t)m * DIM + hbase]
                                     : &kbuf[(size_t)m * KVD + hbase];
            dst[d0]            = v0 * c0v - v1 * s0v;
            dst[d0 + 1]        = v2 * c1v - v3 * s1v;
            dst[d0 + HALF]     = v0 * s0v - v1 * c0v;
            dst[d0 + HALF + 1] = v2 * s1v - v3 * c1v;
        }
    }
}

// ---------------- causal flash attention (fp32) ----------------
__global__ __launch_bounds__(256) void attn_kernel(
    const float* __restrict__ qbuf, const float* __restrict__ kbuf,
    const float* __restrict__ vbuf, float* __restrict__ ctx)
{
    __shared__ float qs[HD][68];   // qs[d][r] (transposed)
    __shared__ float ks[HD][68];   // ks[d][c] (transposed)
    __shared__ float vs[64][68];   // vs[j][d]
    __shared__ float ps[64][68];   // p[r][c]
    __shared__ float redm[64][17];
    __shared__ float redl[64][17];
    __shared__ float row_mnew[64];
    __shared__ float row_scale[64];
    __shared__ float row_linv[64];

    const int tid = threadIdx.x;
    const int q0 = blockIdx.x * 64;
    const int h = blockIdx.y;
    const int b = blockIdx.z;
    const int kh = h >> 2;   // NH/NKV = 4

    const float* qg = qbuf + (size_t)b * SEQ * DIM + (size_t)h * HD;
    const float* kg = kbuf + (size_t)b * SEQ * KVD + (size_t)kh * HD;
    const float* vg = vbuf + (size_t)b * SEQ * KVD + (size_t)kh * HD;

    const int lr = tid >> 2;   // 0..63
    const int lf = tid & 3;    // 0..3

    // Q tile -> LDS transposed
#pragma unroll
    for (int c = 0; c < 4; c++) {
        int d0 = lf * 4 + 16 * c;
        float4 qv = *(const float4*)&qg[(size_t)(q0 + lr) * DIM + d0];
        qs[d0 + 0][lr] = qv.x; qs[d0 + 1][lr] = qv.y;
        qs[d0 + 2][lr] = qv.z; qs[d0 + 3][lr] = qv.w;
    }

    const int tx = tid & 15, ty = tid >> 4;
    const int r0 = ty * 4, c0 = tx * 4;

    float o[4][4];
#pragma unroll
    for (int i = 0; i < 4; i++)
#pragma unroll
        for (int j = 0; j < 4; j++) o[i][j] = 0.0f;

    float m_run = -INFINITY, l_run = 0.0f, sc_reg = 0.0f;

    const int nchunk = (q0 >> 6) + 1;
    for (int ch = 0; ch < nchunk; ch++) {
        const int kv0 = ch * 64;
        __syncthreads();   // protect LDS tiles from previous iteration readers
        // K (transposed) and V tiles -> LDS
#pragma unroll
        for (int c = 0; c < 4; c++) {
            int d0 = lf * 4 + 16 * c;
            float4 kv = *(const float4*)&kg[(size_t)(kv0 + lr) * KVD + d0];
            ks[d0 + 0][lr] = kv.x; ks[d0 + 1][lr] = kv.y;
            ks[d0 + 2][lr] = kv.z; ks[d0 + 3][lr] = kv.w;
            float4 vv = *(const float4*)&vg[(size_t)(kv0 + lr) * KVD + d0];
            *(float4*)&vs[lr][d0] = vv;
        }
        __syncthreads();

        // S = scale * Q K^T  (+ causal mask on diagonal tile)
        float s[4][4];
#pragma unroll
        for (int i = 0; i < 4; i++)
#pragma unroll
            for (int j = 0; j < 4; j++) s[i][j] = 0.0f;
        for (int d = 0; d < HD; d++) {
            float4 a4 = *(const float4*)&qs[d][r0];
            float4 b4 = *(const float4*)&ks[d][c0];
            float a[4] = {a4.x, a4.y, a4.z, a4.w};
            float bb[4] = {b4.x, b4.y, b4.z, b4.w};
#pragma unroll
            for (int i = 0; i < 4; i++)
#pragma unroll
                for (int j = 0; j < 4; j++)
                    s[i][j] = fmaf(a[i], bb[j], s[i][j]);
        }
        const bool diag = (kv0 == q0);
#pragma unroll
        for (int i = 0; i < 4; i++)
#pragma unroll
            for (int j = 0; j < 4; j++) {
                float sv = s[i][j] * 0.125f;
                if (diag && (c0 + j > r0 + i)) sv = -INFINITY;
                s[i][j] = sv;
            }
        // per-thread row partial max
#pragma unroll
        for (int i = 0; i < 4; i++) {
            float pm = fmaxf(fmaxf(s[i][0], s[i][1]), fmaxf(s[i][2], s[i][3]));
            redm[r0 + i][tx] = pm;
        }
        __syncthreads();
        if (tid < 64) {
            float mc = redm[tid][0];
#pragma unroll
            for (int t2 = 1; t2 < 16; t2++) mc = fmaxf(mc, redm[tid][t2]);
            float mnew = fmaxf(m_run, mc);
            sc_reg = expf(m_run - mnew);
            m_run = mnew;
            row_mnew[tid] = mnew;
            row_scale[tid] = sc_reg;
        }
        __syncthreads();
        // P = exp(S - m); rescale o; partial row sums
#pragma unroll
        for (int i = 0; i < 4; i++) {
            float mn = row_mnew[r0 + i];
            float sc = row_scale[r0 + i];
            float p0 = expf(s[i][0] - mn), p1 = expf(s[i][1] - mn);
            float p2 = expf(s[i][2] - mn), p3 = expf(s[i][3] - mn);
            *(float4*)&ps[r0 + i][c0] = make_float4(p0, p1, p2, p3);
            redl[r0 + i][tx] = p0 + p1 + p2 + p3;
#pragma unroll
            for (int j = 0; j < 4; j++) o[i][j] *= sc;
        }
        __syncthreads();
        if (tid < 64) {
            float lc = 0.0f;
#pragma unroll
            for (int t2 = 0; t2 < 16; t2++) lc += redl[tid][t2];
            l_run = l_run * sc_reg + lc;
        }
        // O += P V
        for (int j = 0; j < 64; j++) {
            float4 v4 = *(const float4*)&vs[j][c0];
            float vv[4] = {v4.x, v4.y, v4.z, v4.w};
            float pr[4];
#pragma unroll
            for (int i = 0; i < 4; i++) pr[i] = ps[r0 + i][j];
#pragma unroll
            for (int i = 0; i < 4; i++)
#pragma unroll
                for (int jj = 0; jj < 4; jj++)
                    o[i][jj] = fmaf(pr[i], vv[jj], o[i][jj]);
        }
    }
    if (tid < 64) row_linv[tid] = 1.0f / l_run;
    __syncthreads();
#pragma unroll
    for (int i = 0; i < 4; i++) {
        float inv = row_linv[r0 + i];
        float4 ov = make_float4(o[i][0] * inv, o[i][1] * inv,
                                o[i][2] * inv, o[i][3] * inv);
        *(float4*)&ctx[(size_t)(b * SEQ + q0 + r0 + i) * DIM + h * HD + c0] = ov;
    }
}

// ---------------- output projection ----------------
__global__ __launch_bounds__(256) void out_proj_kernel(
    const float* __restrict__ ctx, const float* __restrict__ Wo,
    const float* __restrict__ bo, float* __restrict__ out)
{
    __shared__ float As[BKT][68];
    __shared__ float Bs[BKT][68];
    const int n0 = blockIdx.x * BN;
    const int m0 = blockIdx.y * BM;
    float acc[4][4];
    gemm64(ctx, DIM, Wo, DIM, m0, n0, DIM, acc, As, Bs);
    const int tid = threadIdx.x;
    const int tx = tid & 15, ty = tid >> 4;
#pragma unroll
    for (int i = 0; i < 4; i++) {
        const int m = m0 + ty * 4 + i;
        float4 ov = make_float4(acc[i][0] + bo[n0 + tx * 4 + 0],
                                acc[i][1] + bo[n0 + tx * 4 + 1],
                                acc[i][2] + bo[n0 + tx * 4 + 2],
                                acc[i][3] + bo[n0 + tx * 4 + 3]);
        *(float4*)&out[(size_t)m * DIM + n0 + tx * 4] = ov;
    }
}

extern "C" void kernel_launch(void* const* d_in, const int* in_sizes, int n_in,
                              void* d_out, int out_size, void* d_ws, size_t ws_size,
                              hipStream_t stream) {
    (void)in_sizes; (void)n_in; (void)out_size; (void)ws_size;
    const float* x  = (const float*)d_in[0];
    const float* Wq = (const float*)d_in[1];
    const float* bq = (const float*)d_in[2];
    const float* Wk = (const float*)d_in[3];
    const float* bk = (const float*)d_in[4];
    const float* Wv = (const float*)d_in[5];
    const float* bv = (const float*)d_in[6];
    const float* Wo = (const float*)d_in[7];
    const float* bo = (const float*)d_in[8];
    float* out = (float*)d_out;
    float* ws = (float*)d_ws;

    float* qbuf = ws;                       // 4,194,304
    float* kbuf = ws + 4194304;             // 1,048,576
    float* vbuf = ws + 5242880;             // 1,048,576
    float* ctx  = ws + 6291456;             // 4,194,304
    float* cosb = ws + 10485760;            // 65,536
    float* sinb = ws + 10551296;            // 65,536

    hipLaunchKernelGGL(rope_table_kernel, dim3((SEQ * HALF + 255) / 256), dim3(256), 0, stream,
                       cosb, sinb);
    hipLaunchKernelGGL(qkv_rope_kernel, dim3(NTOT / BN, MTOT / BM), dim3(256), 0, stream,
                       x, Wq, bq, Wk, bk, Wv, bv, cosb, sinb, qbuf, kbuf, vbuf);
    hipLaunchKernelGGL(attn_kernel, dim3(SEQ / 64, NH, NB), dim3(256), 0, stream,
                       qbuf, kbuf, vbuf, ctx);
    hipLaunchKernelGGL(out_proj_kernel, dim3(DIM / BN, MTOT / BM), dim3(256), 0, stream,
                       ctx, Wo, bo, out);
}

// Round 2
// 205.381 us; speedup vs baseline: 3.7363x; 3.7363x over previous
//
#include <hip/hip_runtime.h>
#include <math.h>

#define DIM 1024
#define NH 16
#define NKV 4
#define HD 64
#define HALF 32
#define NB 2
#define SEQ 2048
#define KVD 256         // NKV*HD
#define MTOT 4096       // NB*SEQ
#define SCALE 0.125f

typedef __bf16 bf16x8 __attribute__((ext_vector_type(8)));
typedef float f32x4 __attribute__((ext_vector_type(4)));
typedef unsigned short u16x8 __attribute__((ext_vector_type(8)));

#define MFMA16(a, b, c) __builtin_amdgcn_mfma_f32_16x16x32_bf16(a, b, c, 0, 0, 0)

__device__ __forceinline__ unsigned short f2bf(float f) {
    unsigned int u = __float_as_uint(f);
    u = (u + 0x7fffu + ((u >> 16) & 1u)) >> 16;
    return (unsigned short)u;
}

// async 16B global->LDS: LDS dest = wave-uniform base + lane*16
__device__ __forceinline__ void gll16(const unsigned short* g, unsigned short* l) {
    __builtin_amdgcn_global_load_lds((const __attribute__((address_space(1))) void*)g,
                                     (__attribute__((address_space(3))) void*)l, 16, 0, 0);
}

// ---------------- rope cos/sin table (fp32, [t][32]) ----------------
__global__ __launch_bounds__(256) void rope_table_kernel(float* __restrict__ cosb,
                                                         float* __restrict__ sinb)
{
    int idx = blockIdx.x * 256 + threadIdx.x;
    if (idx >= SEQ * HALF) return;
    int t = idx >> 5;
    int d = idx & 31;
    float e = (float)(2 * d) / (float)HD;
    float invf = 1.0f / powf(10000.0f, e);
    float f = (float)t * invf;
    cosb[idx] = cosf(f);
    sinb[idx] = sinf(f);
}

// ---------------- x fp32 -> bf16 ----------------
__global__ __launch_bounds__(256) void conv_x_kernel(const float* __restrict__ x,
                                                     unsigned short* __restrict__ xb)
{
    int i = (blockIdx.x * 256 + threadIdx.x) * 8;
    float4 v0 = *(const float4*)&x[i];
    float4 v1 = *(const float4*)&x[i + 4];
    u16x8 o;
    o[0] = f2bf(v0.x); o[1] = f2bf(v0.y); o[2] = f2bf(v0.z); o[3] = f2bf(v0.w);
    o[4] = f2bf(v1.x); o[5] = f2bf(v1.y); o[6] = f2bf(v1.z); o[7] = f2bf(v1.w);
    *(u16x8*)&xb[i] = o;
}

// ---------------- weight transpose+convert: W[k][n] f32 -> Wt[n][k] bf16 ----------------
__global__ __launch_bounds__(256) void transpose_w_kernel(
    const float* __restrict__ Wq, const float* __restrict__ Wk,
    const float* __restrict__ Wv, const float* __restrict__ Wo,
    unsigned short* __restrict__ qt, unsigned short* __restrict__ kt,
    unsigned short* __restrict__ vt, unsigned short* __restrict__ ot)
{
    __shared__ float tile[64][65];
    const float* W; unsigned short* Wt; int N;
    switch (blockIdx.z) {
        case 0: W = Wq; Wt = qt; N = DIM; break;
        case 1: W = Wk; Wt = kt; N = KVD; break;
        case 2: W = Wv; Wt = vt; N = KVD; break;
        default: W = Wo; Wt = ot; N = DIM; break;
    }
    const int n0 = blockIdx.x * 64;
    if (n0 >= N) return;
    const int k0 = blockIdx.y * 64;
    const int tid = threadIdx.x;
    const int row = tid >> 2, coff = (tid & 3) * 16;
#pragma unroll
    for (int i = 0; i < 4; i++) {
        float4 v = *(const float4*)&W[(size_t)(k0 + row) * N + n0 + coff + i * 4];
        tile[row][coff + i * 4 + 0] = v.x; tile[row][coff + i * 4 + 1] = v.y;
        tile[row][coff + i * 4 + 2] = v.z; tile[row][coff + i * 4 + 3] = v.w;
    }
    __syncthreads();
    u16x8 a, b;
#pragma unroll
    for (int i = 0; i < 8; i++) a[i] = f2bf(tile[coff + i][row]);
#pragma unroll
    for (int i = 0; i < 8; i++) b[i] = f2bf(tile[coff + 8 + i][row]);
    *(u16x8*)&Wt[(size_t)(n0 + row) * DIM + k0 + coff] = a;
    *(u16x8*)&Wt[(size_t)(n0 + row) * DIM + k0 + coff + 8] = b;
}

// ---------------- fused QKV GEMM (bf16 MFMA) + bias + RoPE ----------------
// A = xb [4096][1024], B = Wt [n][k]; tile 128x128, BK=32, 4 waves 2x2
__global__ __launch_bounds__(256) void qkv_gemm_kernel(
    const unsigned short* __restrict__ xb,
    const unsigned short* __restrict__ wqt, const unsigned short* __restrict__ wkt,
    const unsigned short* __restrict__ wvt,
    const float* __restrict__ bq, const float* __restrict__ bk, const float* __restrict__ bv,
    const float* __restrict__ cosb, const float* __restrict__ sinb,
    unsigned short* __restrict__ qbuf, unsigned short* __restrict__ kbuf,
    unsigned short* __restrict__ vbuf)
{
    __shared__ unsigned short As[128 * 32];
    __shared__ unsigned short Bs[128 * 32];
    const int tid = threadIdx.x;
    const int lane = tid & 63, w = tid >> 6;
    const int l15 = lane & 15, lg = lane >> 4;
    const int m0 = blockIdx.y * 128;
    const int n0g = blockIdx.x * 128;

    const unsigned short* Wt; const float* bias; int n0, mode;
    if (n0g < DIM)            { Wt = wqt; bias = bq; n0 = n0g; mode = 0; }
    else if (n0g < DIM + KVD) { Wt = wkt; bias = bk; n0 = n0g - DIM; mode = 1; }
    else                      { Wt = wvt; bias = bv; n0 = n0g - DIM - KVD; mode = 2; }

    const int wr = w >> 1, wc = w & 1;   // wave tile 64x64 at (wr*64, wc*64)

    f32x4 acc[4][4];
#pragma unroll
    for (int i = 0; i < 4; i++)
#pragma unroll
        for (int j = 0; j < 4; j++) acc[i][j] = (f32x4){0.f, 0.f, 0.f, 0.f};

    for (int k0 = 0; k0 < DIM; k0 += 32) {
        __syncthreads();
        // stage A and B tiles: 512 slots each of 16B; slot S: row=S>>2, chunk=S&3
#pragma unroll
        for (int i = 0; i < 2; i++) {
            int S = i * 256 + w * 64 + lane;
            int r = S >> 2, c8 = (S & 3) * 8;
            gll16(xb + (size_t)(m0 + r) * DIM + k0 + c8, &As[(i * 256 + w * 64) * 8]);
            gll16(Wt + (size_t)(n0 + r) * DIM + k0 + c8, &Bs[(i * 256 + w * 64) * 8]);
        }
        __syncthreads();
        bf16x8 af[4], bfr[4];
#pragma unroll
        for (int r = 0; r < 4; r++)
            af[r] = *(const bf16x8*)&As[(wr * 64 + r * 16 + l15) * 32 + lg * 8];
#pragma unroll
        for (int c = 0; c < 4; c++)
            bfr[c] = *(const bf16x8*)&Bs[(wc * 64 + c * 16 + l15) * 32 + lg * 8];
#pragma unroll
        for (int r = 0; r < 4; r++)
#pragma unroll
            for (int c = 0; c < 4; c++)
                acc[r][c] = MFMA16(af[r], bfr[c], acc[r][c]);
    }

    // epilogue: C/D layout col = l15 (+16*ct), row = lg*4+q (+16*rt)
    const int nloc = n0 + wc * 64;             // head-aligned 64-col strip
    const bool even = (l15 & 1) == 0;
#pragma unroll
    for (int rt = 0; rt < 4; rt++) {
#pragma unroll
        for (int ct = 0; ct < 4; ct++) {
            const int c = ct * 16 + l15;       // 0..63 within head strip
            const float bsv = bias[nloc + c];
            const int p = c >> 1;
#pragma unroll
            for (int q = 0; q < 4; q++) {
                const int mrow = m0 + wr * 64 + rt * 16 + lg * 4 + q;
                float val = acc[rt][ct][q] + bsv;
                if (mode == 2) {
                    vbuf[(size_t)mrow * KVD + nloc + c] = f2bf(val);
                } else {
                    float prt = __shfl_xor(val, 1);
                    const int t = mrow & (SEQ - 1);
                    float cs = cosb[t * HALF + p];
                    float sn = sinb[t * HALF + p];
                    float outv = even ? (val * cs - prt * sn) : (prt * sn - val * cs);
                    int outc = even ? p : (p + 32);
                    if (mode == 0) qbuf[(size_t)mrow * DIM + nloc + outc] = f2bf(outv);
                    else           kbuf[(size_t)mrow * KVD + nloc + outc] = f2bf(outv);
                }
            }
        }
    }
}

// ---------------- flash attention, bf16 MFMA ----------------
// block: 64 q-rows, 4 waves x 16 rows; 64-key chunks
__global__ __launch_bounds__(256) void attn_mfma_kernel(
    const unsigned short* __restrict__ qb, const unsigned short* __restrict__ kb,
    const unsigned short* __restrict__ vb, unsigned short* __restrict__ ctx)
{
    __shared__ unsigned short Qs[64 * 64];   // [row][d] swizzled: ushort idx = r*64 + (d ^ ((r&7)<<3))
    __shared__ unsigned short Ks[64 * 64];   // [key][d] same swizzle
    __shared__ unsigned short Vt[64 * 64];   // [d][j]   same swizzle on j
    __shared__ unsigned short Ps[4][16 * 64];// per-wave [r][j] same swizzle on j

    const int tid = threadIdx.x;
    const int lane = tid & 63, w = tid >> 6;
    const int l15 = lane & 15, lg = lane >> 4, l7 = lane & 7;
    const int q0 = blockIdx.x * 64;
    const int h = blockIdx.y;
    const int b = blockIdx.z;
    const int kh = h >> 2;

    const unsigned short* qg = qb + (size_t)b * SEQ * DIM + (size_t)h * HD;
    const unsigned short* kg = kb + (size_t)b * SEQ * KVD + (size_t)kh * HD;
    const unsigned short* vg = vb + (size_t)b * SEQ * KVD + (size_t)kh * HD;

    // ---- stage Q (pre-swizzled global source, linear LDS dest) ----
#pragma unroll
    for (int i = 0; i < 2; i++) {
        int S = i * 256 + w * 64 + lane;      // 16B slot; row = S>>3, quad = S&7
        int r = S >> 3, qd = S & 7;
        int d8 = (qd ^ (r & 7)) * 8;
        gll16(qg + (size_t)(q0 + r) * DIM + d8, &Qs[(i * 256 + w * 64) * 8]);
    }

    f32x4 o[4];
#pragma unroll
    for (int i = 0; i < 4; i++) o[i] = (f32x4){0.f, 0.f, 0.f, 0.f};
    float mrun[4] = {-INFINITY, -INFINITY, -INFINITY, -INFINITY};
    float lrun[4] = {0.f, 0.f, 0.f, 0.f};

    const int nch = (q0 >> 6) + 1;
    for (int ch = 0; ch < nch; ch++) {
        const int kv0 = ch * 64;
        __syncthreads();   // all waves done with previous Ks/Vt
        // K chunk -> Ks (swizzled via global source)
#pragma unroll
        for (int i = 0; i < 2; i++) {
            int S = i * 256 + w * 64 + lane;
            int r = S >> 3, qd = S & 7;
            int d8 = (qd ^ (r & 7)) * 8;
            gll16(kg + (size_t)(kv0 + r) * KVD + d8, &Ks[(i * 256 + w * 64) * 8]);
        }
        // V chunk -> Vt transposed (reg-staged): wave w handles d-range w*16..+15, lane = key j
        {
            const int j = lane;
            const unsigned short* vrow = vg + (size_t)(kv0 + j) * KVD + w * 16;
            u16x8 va = *(const u16x8*)vrow;
            u16x8 vb2 = *(const u16x8*)(vrow + 8);
#pragma unroll
            for (int e = 0; e < 8; e++) {
                int d = w * 16 + e;
                Vt[d * 64 + (j ^ ((d & 7) << 3))] = va[e];
            }
#pragma unroll
            for (int e = 0; e < 8; e++) {
                int d = w * 16 + 8 + e;
                Vt[d * 64 + (j ^ ((d & 7) << 3))] = vb2[e];
            }
        }
        __syncthreads();   // staging complete (drains vmcnt for global_load_lds)

        // ---- S = Q K^T for wave's 16 rows x 64 keys ----
        f32x4 sacc[4];
#pragma unroll
        for (int i = 0; i < 4; i++) sacc[i] = (f32x4){0.f, 0.f, 0.f, 0.f};
#pragma unroll
        for (int s = 0; s < 2; s++) {
            const int qrow = w * 16 + l15;
            bf16x8 aq = *(const bf16x8*)&Qs[qrow * 64 + ((s * 32 + lg * 8) ^ ((qrow & 7) << 3))];
#pragma unroll
            for (int ct = 0; ct < 4; ct++) {
                const int krow = ct * 16 + l15;
                bf16x8 bk2 = *(const bf16x8*)&Ks[krow * 64 + ((s * 32 + lg * 8) ^ ((krow & 7) << 3))];
                sacc[ct] = MFMA16(aq, bk2, sacc[ct]);
            }
        }

        // ---- softmax (in-register; row r = lg*4+q of wave strip) ----
        const bool diag = (kv0 == q0);
        float mx[4];
#pragma unroll
        for (int q = 0; q < 4; q++) {
            const int rl = w * 16 + lg * 4 + q;   // local row in 64-tile
            float a0 = sacc[0][q] * SCALE, a1 = sacc[1][q] * SCALE;
            float a2 = sacc[2][q] * SCALE, a3 = sacc[3][q] * SCALE;
            if (diag) {
                if (0 * 16 + l15 > rl) a0 = -INFINITY;
                if (1 * 16 + l15 > rl) a1 = -INFINITY;
                if (2 * 16 + l15 > rl) a2 = -INFINITY;
                if (3 * 16 + l15 > rl) a3 = -INFINITY;
            }
            sacc[0][q] = a0; sacc[1][q] = a1; sacc[2][q] = a2; sacc[3][q] = a3;
            mx[q] = fmaxf(fmaxf(a0, a1), fmaxf(a2, a3));
        }
#pragma unroll
        for (int msk = 1; msk < 16; msk <<= 1)
#pragma unroll
            for (int q = 0; q < 4; q++) mx[q] = fmaxf(mx[q], __shfl_xor(mx[q], msk));
        float al[4];
#pragma unroll
        for (int q = 0; q < 4; q++) {
            float mn = fmaxf(mrun[q], mx[q]);
            al[q] = __expf(mrun[q] - mn);
            mrun[q] = mn;
        }
        float rs[4] = {0.f, 0.f, 0.f, 0.f};
#pragma unroll
        for (int ct = 0; ct < 4; ct++) {
#pragma unroll
            for (int q = 0; q < 4; q++) {
                float p = __expf(sacc[ct][q] - mrun[q]);
                rs[q] += p;
                const int r = lg * 4 + q;
                const int c = ct * 16 + l15;
                Ps[w][r * 64 + (c ^ ((r & 7) << 3))] = f2bf(p);
            }
        }
#pragma unroll
        for (int msk = 1; msk < 16; msk <<= 1)
#pragma unroll
            for (int q = 0; q < 4; q++) rs[q] += __shfl_xor(rs[q], msk);
#pragma unroll
        for (int q = 0; q < 4; q++) lrun[q] = lrun[q] * al[q] + rs[q];
#pragma unroll
        for (int dt = 0; dt < 4; dt++)
#pragma unroll
            for (int q = 0; q < 4; q++) o[dt][q] *= al[q];

        // ---- O += P V ----
#pragma unroll
        for (int s = 0; s < 2; s++) {
            const int pr = l15;
            bf16x8 ap = *(const bf16x8*)&Ps[w][pr * 64 + ((s * 32 + lg * 8) ^ ((pr & 7) << 3))];
#pragma unroll
            for (int dt = 0; dt < 4; dt++) {
                const int d = dt * 16 + l15;
                bf16x8 bv2 = *(const bf16x8*)&Vt[d * 64 + ((s * 32 + lg * 8) ^ ((d & 7) << 3))];
                o[dt] = MFMA16(ap, bv2, o[dt]);
            }
        }
    }

    // ---- write ctx (bf16) ----
#pragma unroll
    for (int dt = 0; dt < 4; dt++) {
#pragma unroll
        for (int q = 0; q < 4; q++) {
            float inv = 1.0f / lrun[q];
            const int mrow = b * SEQ + q0 + w * 16 + lg * 4 + q;
            ctx[(size_t)mrow * DIM + h * HD + dt * 16 + l15] = f2bf(o[dt][q] * inv);
        }
    }
    (void)l7;
}

// ---------------- out projection (bf16 MFMA, fp32 out) ----------------
__global__ __launch_bounds__(256) void outproj_kernel(
    const unsigned short* __restrict__ ctx, const unsigned short* __restrict__ wot,
    const float* __restrict__ bo, float* __restrict__ out)
{
    __shared__ unsigned short As[128 * 32];
    __shared__ unsigned short Bs[128 * 32];
    const int tid = threadIdx.x;
    const int lane = tid & 63, w = tid >> 6;
    const int l15 = lane & 15, lg = lane >> 4;
    const int m0 = blockIdx.y * 128;
    const int n0 = blockIdx.x * 128;
    const int wr = w >> 1, wc = w & 1;

    f32x4 acc[4][4];
#pragma unroll
    for (int i = 0; i < 4; i++)
#pragma unroll
        for (int j = 0; j < 4; j++) acc[i][j] = (f32x4){0.f, 0.f, 0.f, 0.f};

    for (int k0 = 0; k0 < DIM; k0 += 32) {
        __syncthreads();
#pragma unroll
        for (int i = 0; i < 2; i++) {
            int S = i * 256 + w * 64 + lane;
            int r = S >> 2, c8 = (S & 3) * 8;
            gll16(ctx + (size_t)(m0 + r) * DIM + k0 + c8, &As[(i * 256 + w * 64) * 8]);
            gll16(wot + (size_t)(n0 + r) * DIM + k0 + c8, &Bs[(i * 256 + w * 64) * 8]);
        }
        __syncthreads();
        bf16x8 af[4], bfr[4];
#pragma unroll
        for (int r = 0; r < 4; r++)
            af[r] = *(const bf16x8*)&As[(wr * 64 + r * 16 + l15) * 32 + lg * 8];
#pragma unroll
        for (int c = 0; c < 4; c++)
            bfr[c] = *(const bf16x8*)&Bs[(wc * 64 + c * 16 + l15) * 32 + lg * 8];
#pragma unroll
        for (int r = 0; r < 4; r++)
#pragma unroll
            for (int c = 0; c < 4; c++)
                acc[r][c] = MFMA16(af[r], bfr[c], acc[r][c]);
    }

#pragma unroll
    for (int rt = 0; rt < 4; rt++) {
#pragma unroll
        for (int ct = 0; ct < 4; ct++) {
            const int ncol = n0 + wc * 64 + ct * 16 + l15;
            const float bsv = bo[ncol];
#pragma unroll
            for (int q = 0; q < 4; q++) {
                const int mrow = m0 + wr * 64 + rt * 16 + lg * 4 + q;
                out[(size_t)mrow * DIM + ncol] = acc[rt][ct][q] + bsv;
            }
        }
    }
}

extern "C" void kernel_launch(void* const* d_in, const int* in_sizes, int n_in,
                              void* d_out, int out_size, void* d_ws, size_t ws_size,
                              hipStream_t stream) {
    (void)in_sizes; (void)n_in; (void)out_size; (void)ws_size;
    const float* x  = (const float*)d_in[0];
    const float* Wq = (const float*)d_in[1];
    const float* bq = (const float*)d_in[2];
    const float* Wk = (const float*)d_in[3];
    const float* bk = (const float*)d_in[4];
    const float* Wv = (const float*)d_in[5];
    const float* bv = (const float*)d_in[6];
    const float* Wo = (const float*)d_in[7];
    const float* bo = (const float*)d_in[8];
    float* out = (float*)d_out;
    char* ws = (char*)d_ws;

    unsigned short* xb  = (unsigned short*)(ws);              //  8 MB  [4096][1024]
    unsigned short* qbf = (unsigned short*)(ws + 8388608);    //  8 MB  [4096][1024]
    unsigned short* kbf = (unsigned short*)(ws + 16777216);   //  2 MB  [4096][256]
    unsigned short* vbf = (unsigned short*)(ws + 18874368);   //  2 MB  [4096][256]
    unsigned short* ctx = (unsigned short*)(ws + 20971520);   //  8 MB  [4096][1024]
    unsigned short* wqt = (unsigned short*)(ws + 29360128);   //  2 MB  [1024][1024]
    unsigned short* wkt = (unsigned short*)(ws + 31457280);   // .5 MB  [256][1024]
    unsigned short* wvt = (unsigned short*)(ws + 31981568);   // .5 MB
    unsigned short* wot = (unsigned short*)(ws + 32505856);   //  2 MB
    float* cosb = (float*)(ws + 34603008);                    // .25 MB [2048][32]
    float* sinb = (float*)(ws + 34865152);

    hipLaunchKernelGGL(rope_table_kernel, dim3(256), dim3(256), 0, stream, cosb, sinb);
    hipLaunchKernelGGL(conv_x_kernel, dim3(2048), dim3(256), 0, stream, x, xb);
    hipLaunchKernelGGL(transpose_w_kernel, dim3(16, 16, 4), dim3(256), 0, stream,
                       Wq, Wk, Wv, Wo, wqt, wkt, wvt, wot);
    hipLaunchKernelGGL(qkv_gemm_kernel, dim3(12, 32), dim3(256), 0, stream,
                       xb, wqt, wkt, wvt, bq, bk, bv, cosb, sinb, qbf, kbf, vbf);
    hipLaunchKernelGGL(attn_mfma_kernel, dim3(SEQ / 64, NH, NB), dim3(256), 0, stream,
                       qbf, kbf, vbf, ctx);
    hipLaunchKernelGGL(outproj_kernel, dim3(8, 32), dim3(256), 0, stream,
                       ctx, wot, bo, out);
}

// Round 4
// 155.332 us; speedup vs baseline: 4.9401x; 1.3222x over previous
//
#include <hip/hip_runtime.h>
#include <math.h>

#define DIM 1024
#define NH 16
#define NKV 4
#define HD 64
#define HALF 32
#define NB 2
#define SEQ 2048
#define KVD 256         // NKV*HD
#define MTOT 4096       // NB*SEQ

typedef __bf16 bf16x8 __attribute__((ext_vector_type(8)));
typedef float f32x4 __attribute__((ext_vector_type(4)));
typedef unsigned short u16x8 __attribute__((ext_vector_type(8)));

#define MFMA16(a, b, c) __builtin_amdgcn_mfma_f32_16x16x32_bf16(a, b, c, 0, 0, 0)

__device__ __forceinline__ unsigned short f2bf(float f) {
    unsigned int u = __float_as_uint(f);
    u = (u + 0x7fffu + ((u >> 16) & 1u)) >> 16;
    return (unsigned short)u;
}

__device__ __forceinline__ unsigned pack2bf(float lo, float hi) {
    return (unsigned)f2bf(lo) | ((unsigned)f2bf(hi) << 16);
}

// async 16B global->LDS: LDS dest = wave-uniform base + lane*16
__device__ __forceinline__ void gll16(const unsigned short* g, unsigned short* l) {
    __builtin_amdgcn_global_load_lds((const __attribute__((address_space(1))) void*)g,
                                     (__attribute__((address_space(3))) void*)l, 16, 0, 0);
}

// ---------------- rope cos/sin table (fp32, [t][32]) ----------------
__global__ __launch_bounds__(256) void rope_table_kernel(float* __restrict__ cosb,
                                                         float* __restrict__ sinb)
{
    int idx = blockIdx.x * 256 + threadIdx.x;
    if (idx >= SEQ * HALF) return;
    int t = idx >> 5;
    int d = idx & 31;
    float e = (float)(2 * d) / (float)HD;
    float invf = 1.0f / powf(10000.0f, e);
    float f = (float)t * invf;
    cosb[idx] = cosf(f);
    sinb[idx] = sinf(f);
}

// ---------------- x fp32 -> bf16 ----------------
__global__ __launch_bounds__(256) void conv_x_kernel(const float* __restrict__ x,
                                                     unsigned short* __restrict__ xb)
{
    int i = (blockIdx.x * 256 + threadIdx.x) * 8;
    float4 v0 = *(const float4*)&x[i];
    float4 v1 = *(const float4*)&x[i + 4];
    u16x8 o;
    o[0] = f2bf(v0.x); o[1] = f2bf(v0.y); o[2] = f2bf(v0.z); o[3] = f2bf(v0.w);
    o[4] = f2bf(v1.x); o[5] = f2bf(v1.y); o[6] = f2bf(v1.z); o[7] = f2bf(v1.w);
    *(u16x8*)&xb[i] = o;
}

// ---------------- weight transpose+convert: W[k][n] f32 -> Wt[n][k] bf16 ----------------
__global__ __launch_bounds__(256) void transpose_w_kernel(
    const float* __restrict__ Wq, const float* __restrict__ Wk,
    const float* __restrict__ Wv, const float* __restrict__ Wo,
    unsigned short* __restrict__ qt, unsigned short* __restrict__ kt,
    unsigned short* __restrict__ vt, unsigned short* __restrict__ ot)
{
    __shared__ float tile[64][65];
    const float* W; unsigned short* Wt; int N;
    switch (blockIdx.z) {
        case 0: W = Wq; Wt = qt; N = DIM; break;
        case 1: W = Wk; Wt = kt; N = KVD; break;
        case 2: W = Wv; Wt = vt; N = KVD; break;
        default: W = Wo; Wt = ot; N = DIM; break;
    }
    const int n0 = blockIdx.x * 64;
    if (n0 >= N) return;
    const int k0 = blockIdx.y * 64;
    const int tid = threadIdx.x;
    const int row = tid >> 2, coff = (tid & 3) * 16;
#pragma unroll
    for (int i = 0; i < 4; i++) {
        float4 v = *(const float4*)&W[(size_t)(k0 + row) * N + n0 + coff + i * 4];
        tile[row][coff + i * 4 + 0] = v.x; tile[row][coff + i * 4 + 1] = v.y;
        tile[row][coff + i * 4 + 2] = v.z; tile[row][coff + i * 4 + 3] = v.w;
    }
    __syncthreads();
    u16x8 a, b;
#pragma unroll
    for (int i = 0; i < 8; i++) a[i] = f2bf(tile[coff + i][row]);
#pragma unroll
    for (int i = 0; i < 8; i++) b[i] = f2bf(tile[coff + 8 + i][row]);
    *(u16x8*)&Wt[(size_t)(n0 + row) * DIM + k0 + coff] = a;
    *(u16x8*)&Wt[(size_t)(n0 + row) * DIM + k0 + coff + 8] = b;
}

// ---------------- fused QKV GEMM (bf16 MFMA) + bias + RoPE (+ q pre-scale) ----------------
__global__ __launch_bounds__(256) void qkv_gemm_kernel(
    const unsigned short* __restrict__ xb,
    const unsigned short* __restrict__ wqt, const unsigned short* __restrict__ wkt,
    const unsigned short* __restrict__ wvt,
    const float* __restrict__ bq, const float* __restrict__ bk, const float* __restrict__ bv,
    const float* __restrict__ cosb, const float* __restrict__ sinb,
    unsigned short* __restrict__ qbuf, unsigned short* __restrict__ kbuf,
    unsigned short* __restrict__ vbuf)
{
    __shared__ unsigned short As[128 * 32];
    __shared__ unsigned short Bs[128 * 32];
    const int tid = threadIdx.x;
    const int lane = tid & 63, w = tid >> 6;
    const int l15 = lane & 15, lg = lane >> 4;
    const int m0 = blockIdx.y * 128;
    const int n0g = blockIdx.x * 128;

    const unsigned short* Wt; const float* bias; int n0, mode;
    if (n0g < DIM)            { Wt = wqt; bias = bq; n0 = n0g; mode = 0; }
    else if (n0g < DIM + KVD) { Wt = wkt; bias = bk; n0 = n0g - DIM; mode = 1; }
    else                      { Wt = wvt; bias = bv; n0 = n0g - DIM - KVD; mode = 2; }

    const int wr = w >> 1, wc = w & 1;

    f32x4 acc[4][4];
#pragma unroll
    for (int i = 0; i < 4; i++)
#pragma unroll
        for (int j = 0; j < 4; j++) acc[i][j] = (f32x4){0.f, 0.f, 0.f, 0.f};

    for (int k0 = 0; k0 < DIM; k0 += 32) {
        __syncthreads();
#pragma unroll
        for (int i = 0; i < 2; i++) {
            int S = i * 256 + w * 64 + lane;
            int r = S >> 2, c8 = (S & 3) * 8;
            gll16(xb + (size_t)(m0 + r) * DIM + k0 + c8, &As[(i * 256 + w * 64) * 8]);
            gll16(Wt + (size_t)(n0 + r) * DIM + k0 + c8, &Bs[(i * 256 + w * 64) * 8]);
        }
        __syncthreads();
        bf16x8 af[4], bfr[4];
#pragma unroll
        for (int r = 0; r < 4; r++)
            af[r] = *(const bf16x8*)&As[(wr * 64 + r * 16 + l15) * 32 + lg * 8];
#pragma unroll
        for (int c = 0; c < 4; c++)
            bfr[c] = *(const bf16x8*)&Bs[(wc * 64 + c * 16 + l15) * 32 + lg * 8];
#pragma unroll
        for (int r = 0; r < 4; r++)
#pragma unroll
            for (int c = 0; c < 4; c++)
                acc[r][c] = MFMA16(af[r], bfr[c], acc[r][c]);
    }

    const int nloc = n0 + wc * 64;
    const bool even = (l15 & 1) == 0;
#pragma unroll
    for (int rt = 0; rt < 4; rt++) {
#pragma unroll
        for (int ct = 0; ct < 4; ct++) {
            const int c = ct * 16 + l15;
            const float bsv = bias[nloc + c];
            const int p = c >> 1;
#pragma unroll
            for (int q = 0; q < 4; q++) {
                const int mrow = m0 + wr * 64 + rt * 16 + lg * 4 + q;
                float val = acc[rt][ct][q] + bsv;
                if (mode == 2) {
                    vbuf[(size_t)mrow * KVD + nloc + c] = f2bf(val);
                } else {
                    float prt = __shfl_xor(val, 1);
                    const int t = mrow & (SEQ - 1);
                    float cs = cosb[t * HALF + p];
                    float sn = sinb[t * HALF + p];
                    float outv = even ? (val * cs - prt * sn) : (prt * sn - val * cs);
                    int outc = even ? p : (p + 32);
                    if (mode == 0) qbuf[(size_t)mrow * DIM + nloc + outc] = f2bf(outv * 0.125f);
                    else           kbuf[(size_t)mrow * KVD + nloc + outc] = f2bf(outv);
                }
            }
        }
    }
}

// ---------------- V transpose: vbuf[b*SEQ+t][kh*64+d] -> vT[(b*4+kh)*64+d][t] ----------------
__global__ __launch_bounds__(256) void transpose_v_kernel(
    const unsigned short* __restrict__ vbuf, unsigned short* __restrict__ vT)
{
    __shared__ unsigned short tile[64][68];
    const int t0 = blockIdx.x * 64;
    const int bk = blockIdx.y;           // b*4 + kh
    const int b = bk >> 2, kh = bk & 3;
    const int tid = threadIdx.x;
    const int r = tid >> 2, c8 = (tid & 3) * 16;
    const unsigned short* src = vbuf + ((size_t)b * SEQ + t0) * KVD + kh * 64;
    u16x8 va = *(const u16x8*)&src[(size_t)r * KVD + c8];
    u16x8 vb = *(const u16x8*)&src[(size_t)r * KVD + c8 + 8];
#pragma unroll
    for (int e = 0; e < 8; e++) tile[r][c8 + e] = va[e];
#pragma unroll
    for (int e = 0; e < 8; e++) tile[r][c8 + 8 + e] = vb[e];
    __syncthreads();
    const int d = tid >> 2, t8 = (tid & 3) * 16;
    unsigned short* dst = vT + ((size_t)bk * 64 + d) * SEQ + t0 + t8;
    u16x8 oa, ob;
#pragma unroll
    for (int e = 0; e < 8; e++) oa[e] = tile[t8 + e][d];
#pragma unroll
    for (int e = 0; e < 8; e++) ob[e] = tile[t8 + 8 + e][d];
    *(u16x8*)&dst[0] = oa;
    *(u16x8*)&dst[8] = ob;
}

// ---------------- flash attention, bf16 MFMA, swapped QK^T in-register softmax ----------------
__global__ __launch_bounds__(256) void attn_mfma_kernel(
    const unsigned short* __restrict__ qb, const unsigned short* __restrict__ kb,
    const unsigned short* __restrict__ vT, unsigned short* __restrict__ ctx)
{
    __shared__ unsigned short Qs[64 * 64];   // [q][d], d XOR-swizzled by (q&7)<<3
    __shared__ unsigned short Ks[64 * 64];   // [key][d], same swizzle
    __shared__ unsigned short Vt[64 * 64];   // [d][j], j swizzled by (d&7)<<3
    __shared__ unsigned Pw[4][16 * 32];      // per-wave P rows: [q=l15][32 u32 words], word^((q&7)<<2)

    const int tid = threadIdx.x;
    const int lane = tid & 63, w = tid >> 6;
    const int l15 = lane & 15, lg = lane >> 4;
    const int q0 = blockIdx.x * 64;
    const int h = blockIdx.y;
    const int b = blockIdx.z;
    const int kh = h >> 2;

    const unsigned short* qg = qb + (size_t)b * SEQ * DIM + (size_t)h * HD;
    const unsigned short* kg = kb + (size_t)b * SEQ * KVD + (size_t)kh * HD;
    const unsigned short* vg = vT + ((size_t)(b * NKV + kh) * HD) * SEQ;

    // ---- stage Q once (pre-swizzled global source, linear LDS dest) ----
#pragma unroll
    for (int i = 0; i < 2; i++) {
        int S = i * 256 + w * 64 + lane;
        int r = S >> 3, qd = S & 7;
        gll16(qg + (size_t)(q0 + r) * DIM + ((qd ^ (r & 7)) * 8), &Qs[(i * 256 + w * 64) * 8]);
    }

    f32x4 o[4];
#pragma unroll
    for (int i = 0; i < 4; i++) o[i] = (f32x4){0.f, 0.f, 0.f, 0.f};
    float mrun = -INFINITY, lrun = 0.f;

    const int qg_row = w * 16 + l15;          // this lane's q row (softmax view)
    const int swzd = (l15 & 7) << 3;          // ushort-index xor for rows with row&7 == l15&7
    unsigned* PW = &Pw[w][l15 * 32];
    const int pswz = (l15 & 7) << 2;          // u32-word xor
    bf16x8 bq0 = {}, bq1 = {};

    const int nch = (q0 >> 6) + 1;
    for (int ch = 0; ch < nch; ch++) {
        const int kv0 = ch * 64;
        __syncthreads();                       // waves done with previous Ks/Vt
#pragma unroll
        for (int i = 0; i < 2; i++) {
            int S = i * 256 + w * 64 + lane;
            int r = S >> 3, qd = S & 7;
            gll16(kg + (size_t)(kv0 + r) * KVD + ((qd ^ (r & 7)) * 8),
                  &Ks[(i * 256 + w * 64) * 8]);
            gll16(vg + (size_t)r * SEQ + kv0 + ((qd ^ (r & 7)) * 8),
                  &Vt[(i * 256 + w * 64) * 8]);
        }
        __syncthreads();                       // staging complete

        if (ch == 0) {   // Q fragments live across the whole loop
            bq0 = *(const bf16x8*)&Qs[qg_row * 64 + ((lg * 8) ^ swzd)];
            bq1 = *(const bf16x8*)&Qs[qg_row * 64 + ((32 + lg * 8) ^ swzd)];
        }

        // ---- S^T = K Q^T : lane holds S[q=l15][key = ct*16 + lg*4 + reg] ----
        f32x4 sacc[4];
#pragma unroll
        for (int i = 0; i < 4; i++) sacc[i] = (f32x4){0.f, 0.f, 0.f, 0.f};
#pragma unroll
        for (int ct = 0; ct < 4; ct++) {
            const int kr = ct * 16 + l15;
            bf16x8 ak = *(const bf16x8*)&Ks[kr * 64 + ((lg * 8) ^ swzd)];
            sacc[ct] = MFMA16(ak, bq0, sacc[ct]);
        }
#pragma unroll
        for (int ct = 0; ct < 4; ct++) {
            const int kr = ct * 16 + l15;
            bf16x8 ak = *(const bf16x8*)&Ks[kr * 64 + ((32 + lg * 8) ^ swzd)];
            sacc[ct] = MFMA16(ak, bq1, sacc[ct]);
        }

        // ---- mask + in-register max ----
        const bool diag = (kv0 == q0);
        float mx = -INFINITY;
#pragma unroll
        for (int ct = 0; ct < 4; ct++) {
#pragma unroll
            for (int r = 0; r < 4; r++) {
                float sv = sacc[ct][r];
                if (diag && (ct * 16 + lg * 4 + r > qg_row)) sv = -INFINITY;
                sacc[ct][r] = sv;
                mx = fmaxf(mx, sv);
            }
        }
        mx = fmaxf(mx, __shfl_xor(mx, 16));
        mx = fmaxf(mx, __shfl_xor(mx, 32));

        float al = 1.0f;
        if (!__all(mx <= mrun + 8.0f)) {       // T13 defer-max
            float mnew = fmaxf(mrun, mx);
            al = __expf(mrun - mnew);
            mrun = mnew;
            float alb0 = __shfl(al, lg * 4 + 0);
            float alb1 = __shfl(al, lg * 4 + 1);
            float alb2 = __shfl(al, lg * 4 + 2);
            float alb3 = __shfl(al, lg * 4 + 3);
#pragma unroll
            for (int dt = 0; dt < 4; dt++) {
                o[dt][0] *= alb0; o[dt][1] *= alb1;
                o[dt][2] *= alb2; o[dt][3] *= alb3;
            }
        }

        // ---- P = exp(S - mrun), row-sum, pack to bf16 pairs ----
        float rs = 0.f;
        unsigned pk0[4], pk1[4];
#pragma unroll
        for (int ct = 0; ct < 4; ct++) {
            float p0 = __expf(sacc[ct][0] - mrun);
            float p1 = __expf(sacc[ct][1] - mrun);
            float p2 = __expf(sacc[ct][2] - mrun);
            float p3 = __expf(sacc[ct][3] - mrun);
            rs += (p0 + p1) + (p2 + p3);
            pk0[ct] = pack2bf(p0, p1);
            pk1[ct] = pack2bf(p2, p3);
        }
        rs += __shfl_xor(rs, 16);
        rs += __shfl_xor(rs, 32);
        lrun = lrun * al + rs;

        // ---- P rows -> per-wave LDS (packed b64, swizzled) ----
#pragma unroll
        for (int ct = 0; ct < 4; ct++) {
            int wrd = (ct * 8 + lg * 2) ^ pswz;
            *(uint2*)&PW[wrd] = make_uint2(pk0[ct], pk1[ct]);
        }

        // ---- O += P V ----
#pragma unroll
        for (int s = 0; s < 2; s++) {
            int wrd = (s * 16 + lg * 4) ^ pswz;
            bf16x8 ap = *(const bf16x8*)&PW[wrd];
#pragma unroll
            for (int dt = 0; dt < 4; dt++) {
                const int d = dt * 16 + l15;
                bf16x8 bv2 = *(const bf16x8*)&Vt[d * 64 + ((s * 32 + lg * 8) ^ ((d & 7) << 3))];
                o[dt] = MFMA16(ap, bv2, o[dt]);
            }
        }
    }

    // ---- normalize + write ctx ----
    float linv = 1.0f / lrun;
    float lb0 = __shfl(linv, lg * 4 + 0);
    float lb1 = __shfl(linv, lg * 4 + 1);
    float lb2 = __shfl(linv, lg * 4 + 2);
    float lb3 = __shfl(linv, lg * 4 + 3);
#pragma unroll
    for (int dt = 0; dt < 4; dt++) {
        const size_t base = (size_t)(b * SEQ + q0 + w * 16 + lg * 4) * DIM + h * HD + dt * 16 + l15;
        ctx[base]           = f2bf(o[dt][0] * lb0);
        ctx[base + DIM]     = f2bf(o[dt][1] * lb1);
        ctx[base + 2 * DIM] = f2bf(o[dt][2] * lb2);
        ctx[base + 3 * DIM] = f2bf(o[dt][3] * lb3);
    }
}

// ---------------- out projection (bf16 MFMA, fp32 out) ----------------
__global__ __launch_bounds__(256) void outproj_kernel(
    const unsigned short* __restrict__ ctx, const unsigned short* __restrict__ wot,
    const float* __restrict__ bo, float* __restrict__ out)
{
    __shared__ unsigned short As[128 * 32];
    __shared__ unsigned short Bs[128 * 32];
    const int tid = threadIdx.x;
    const int lane = tid & 63, w = tid >> 6;
    const int l15 = lane & 15, lg = lane >> 4;
    const int m0 = blockIdx.y * 128;
    const int n0 = blockIdx.x * 128;
    const int wr = w >> 1, wc = w & 1;

    f32x4 acc[4][4];
#pragma unroll
    for (int i = 0; i < 4; i++)
#pragma unroll
        for (int j = 0; j < 4; j++) acc[i][j] = (f32x4){0.f, 0.f, 0.f, 0.f};

    for (int k0 = 0; k0 < DIM; k0 += 32) {
        __syncthreads();
#pragma unroll
        for (int i = 0; i < 2; i++) {
            int S = i * 256 + w * 64 + lane;
            int r = S >> 2, c8 = (S & 3) * 8;
            gll16(ctx + (size_t)(m0 + r) * DIM + k0 + c8, &As[(i * 256 + w * 64) * 8]);
            gll16(wot + (size_t)(n0 + r) * DIM + k0 + c8, &Bs[(i * 256 + w * 64) * 8]);
        }
        __syncthreads();
        bf16x8 af[4], bfr[4];
#pragma unroll
        for (int r = 0; r < 4; r++)
            af[r] = *(const bf16x8*)&As[(wr * 64 + r * 16 + l15) * 32 + lg * 8];
#pragma unroll
        for (int c = 0; c < 4; c++)
            bfr[c] = *(const bf16x8*)&Bs[(wc * 64 + c * 16 + l15) * 32 + lg * 8];
#pragma unroll
        for (int r = 0; r < 4; r++)
#pragma unroll
            for (int c = 0; c < 4; c++)
                acc[r][c] = MFMA16(af[r], bfr[c], acc[r][c]);
    }

#pragma unroll
    for (int rt = 0; rt < 4; rt++) {
#pragma unroll
        for (int ct = 0; ct < 4; ct++) {
            const int ncol = n0 + wc * 64 + ct * 16 + l15;
            const float bsv = bo[ncol];
#pragma unroll
            for (int q = 0; q < 4; q++) {
                const int mrow = m0 + wr * 64 + rt * 16 + lg * 4 + q;
                out[(size_t)mrow * DIM + ncol] = acc[rt][ct][q] + bsv;
            }
        }
    }
}

extern "C" void kernel_launch(void* const* d_in, const int* in_sizes, int n_in,
                              void* d_out, int out_size, void* d_ws, size_t ws_size,
                              hipStream_t stream) {
    (void)in_sizes; (void)n_in; (void)out_size; (void)ws_size;
    const float* x  = (const float*)d_in[0];
    const float* Wq = (const float*)d_in[1];
    const float* bq = (const float*)d_in[2];
    const float* Wk = (const float*)d_in[3];
    const float* bk = (const float*)d_in[4];
    const float* Wv = (const float*)d_in[5];
    const float* bv = (const float*)d_in[6];
    const float* Wo = (const float*)d_in[7];
    const float* bo = (const float*)d_in[8];
    float* out = (float*)d_out;
    char* ws = (char*)d_ws;

    unsigned short* xb  = (unsigned short*)(ws);              //  8 MB
    unsigned short* qbf = (unsigned short*)(ws + 8388608);    //  8 MB
    unsigned short* kbf = (unsigned short*)(ws + 16777216);   //  2 MB
    unsigned short* vbf = (unsigned short*)(ws + 18874368);   //  2 MB
    unsigned short* ctx = (unsigned short*)(ws + 20971520);   //  8 MB
    unsigned short* wqt = (unsigned short*)(ws + 29360128);   //  2 MB
    unsigned short* wkt = (unsigned short*)(ws + 31457280);   // .5 MB
    unsigned short* wvt = (unsigned short*)(ws + 31981568);   // .5 MB
    unsigned short* wot = (unsigned short*)(ws + 32505856);   //  2 MB
    float* cosb = (float*)(ws + 34603008);                    // .25 MB
    float* sinb = (float*)(ws + 34865152);                    // .25 MB
    unsigned short* vTb = (unsigned short*)(ws + 35127296);   //  4 MB  [8][64][2048]

    hipLaunchKernelGGL(rope_table_kernel, dim3(256), dim3(256), 0, stream, cosb, sinb);
    hipLaunchKernelGGL(conv_x_kernel, dim3(2048), dim3(256), 0, stream, x, xb);
    hipLaunchKernelGGL(transpose_w_kernel, dim3(16, 16, 4), dim3(256), 0, stream,
                       Wq, Wk, Wv, Wo, wqt, wkt, wvt, wot);
    hipLaunchKernelGGL(qkv_gemm_kernel, dim3(12, 32), dim3(256), 0, stream,
                       xb, wqt, wkt, wvt, bq, bk, bv, cosb, sinb, qbf, kbf, vbf);
    hipLaunchKernelGGL(transpose_v_kernel, dim3(32, 8), dim3(256), 0, stream, vbf, vTb);
    hipLaunchKernelGGL(attn_mfma_kernel, dim3(SEQ / 64, NH, NB), dim3(256), 0, stream,
                       qbf, kbf, vTb, ctx);
    hipLaunchKernelGGL(outproj_kernel, dim3(8, 32), dim3(256), 0, stream,
                       ctx, wot, bo, out);
}

// Round 5
// 124.714 us; speedup vs baseline: 6.1530x; 1.2455x over previous
//
#include <hip/hip_runtime.h>
#include <math.h>

#define DIM 1024
#define NH 16
#define NKV 4
#define HD 64
#define HALF 32
#define NB 2
#define SEQ 2048
#define KVD 256         // NKV*HD
#define MTOT 4096       // NB*SEQ
#define QSCALE 0.18033688f   // 0.125 * log2(e): softmax runs in exp2 domain

typedef __bf16 bf16x8 __attribute__((ext_vector_type(8)));
typedef float f32x4 __attribute__((ext_vector_type(4)));
typedef unsigned short u16x8 __attribute__((ext_vector_type(8)));

#define MFMA16(a, b, c) __builtin_amdgcn_mfma_f32_16x16x32_bf16(a, b, c, 0, 0, 0)

__device__ __forceinline__ unsigned short f2bf(float f) {
    unsigned int u = __float_as_uint(f);
    u = (u + 0x7fffu + ((u >> 16) & 1u)) >> 16;
    return (unsigned short)u;
}

__device__ __forceinline__ unsigned pack2bf(float lo, float hi) {
    return (unsigned)f2bf(lo) | ((unsigned)f2bf(hi) << 16);
}

// async 16B global->LDS: LDS dest = wave-uniform base + lane*16
__device__ __forceinline__ void gll16(const unsigned short* g, unsigned short* l) {
    __builtin_amdgcn_global_load_lds((const __attribute__((address_space(1))) void*)g,
                                     (__attribute__((address_space(3))) void*)l, 16, 0, 0);
}

// ---------------- merged prep: rope table + x->bf16 + weight transpose ----------------
// blocks [0,256): rope table; [256,2304): conv x; [2304,3328): transpose W
__global__ __launch_bounds__(256) void prep_kernel(
    const float* __restrict__ x,
    const float* __restrict__ Wq, const float* __restrict__ Wk,
    const float* __restrict__ Wv, const float* __restrict__ Wo,
    unsigned short* __restrict__ xb,
    unsigned short* __restrict__ qt, unsigned short* __restrict__ kt,
    unsigned short* __restrict__ vt, unsigned short* __restrict__ ot,
    float* __restrict__ cosb, float* __restrict__ sinb)
{
    __shared__ float tile[64][65];
    const int bx = blockIdx.x;
    const int tid = threadIdx.x;
    if (bx < 256) {
        int idx = bx * 256 + tid;         // 64K entries
        int t = idx >> 5, d = idx & 31;
        float e = (float)(2 * d) / (float)HD;
        float invf = 1.0f / powf(10000.0f, e);
        float f = (float)t * invf;
        cosb[idx] = cosf(f);
        sinb[idx] = sinf(f);
    } else if (bx < 2304) {
        int i = ((bx - 256) * 256 + tid) * 8;
        float4 v0 = *(const float4*)&x[i];
        float4 v1 = *(const float4*)&x[i + 4];
        u16x8 o;
        o[0] = f2bf(v0.x); o[1] = f2bf(v0.y); o[2] = f2bf(v0.z); o[3] = f2bf(v0.w);
        o[4] = f2bf(v1.x); o[5] = f2bf(v1.y); o[6] = f2bf(v1.z); o[7] = f2bf(v1.w);
        *(u16x8*)&xb[i] = o;
    } else {
        int idx2 = bx - 2304;             // 1024 blocks: 4 matrices x 16x16 tiles
        int z = idx2 >> 8, rem = idx2 & 255, xx = rem & 15, yy = rem >> 4;
        const float* W; unsigned short* Wt; int N;
        switch (z) {
            case 0: W = Wq; Wt = qt; N = DIM; break;
            case 1: W = Wk; Wt = kt; N = KVD; break;
            case 2: W = Wv; Wt = vt; N = KVD; break;
            default: W = Wo; Wt = ot; N = DIM; break;
        }
        const int n0 = xx * 64;
        if (n0 >= N) return;
        const int k0 = yy * 64;
        const int row = tid >> 2, coff = (tid & 3) * 16;
#pragma unroll
        for (int i = 0; i < 4; i++) {
            float4 v = *(const float4*)&W[(size_t)(k0 + row) * N + n0 + coff + i * 4];
            tile[row][coff + i * 4 + 0] = v.x; tile[row][coff + i * 4 + 1] = v.y;
            tile[row][coff + i * 4 + 2] = v.z; tile[row][coff + i * 4 + 3] = v.w;
        }
        __syncthreads();
        u16x8 a, b;
#pragma unroll
        for (int i = 0; i < 8; i++) a[i] = f2bf(tile[coff + i][row]);
#pragma unroll
        for (int i = 0; i < 8; i++) b[i] = f2bf(tile[coff + 8 + i][row]);
        *(u16x8*)&Wt[(size_t)(n0 + row) * DIM + k0 + coff] = a;
        *(u16x8*)&Wt[(size_t)(n0 + row) * DIM + k0 + coff + 8] = b;
    }
}

// ---------------- fused QKV GEMM + bias + RoPE; V written transposed ----------------
__global__ __launch_bounds__(256) void qkv_gemm_kernel(
    const unsigned short* __restrict__ xb,
    const unsigned short* __restrict__ wqt, const unsigned short* __restrict__ wkt,
    const unsigned short* __restrict__ wvt,
    const float* __restrict__ bq, const float* __restrict__ bk, const float* __restrict__ bv,
    const float* __restrict__ cosb, const float* __restrict__ sinb,
    unsigned short* __restrict__ qbuf, unsigned short* __restrict__ kbuf,
    unsigned short* __restrict__ vT)
{
    __shared__ unsigned short As[128 * 32];
    __shared__ unsigned short Bs[128 * 32];
    const int tid = threadIdx.x;
    const int lane = tid & 63, w = tid >> 6;
    const int l15 = lane & 15, lg = lane >> 4;
    const int m0 = blockIdx.y * 128;
    const int n0g = blockIdx.x * 128;

    const unsigned short* Wt; const float* bias; int n0, mode;
    if (n0g < DIM)            { Wt = wqt; bias = bq; n0 = n0g; mode = 0; }
    else if (n0g < DIM + KVD) { Wt = wkt; bias = bk; n0 = n0g - DIM; mode = 1; }
    else                      { Wt = wvt; bias = bv; n0 = n0g - DIM - KVD; mode = 2; }

    const int wr = w >> 1, wc = w & 1;

    f32x4 acc[4][4];
#pragma unroll
    for (int i = 0; i < 4; i++)
#pragma unroll
        for (int j = 0; j < 4; j++) acc[i][j] = (f32x4){0.f, 0.f, 0.f, 0.f};

    for (int k0 = 0; k0 < DIM; k0 += 32) {
        __syncthreads();
#pragma unroll
        for (int i = 0; i < 2; i++) {
            int S = i * 256 + w * 64 + lane;
            int r = S >> 2, c8 = (S & 3) * 8;
            gll16(xb + (size_t)(m0 + r) * DIM + k0 + c8, &As[(i * 256 + w * 64) * 8]);
            gll16(Wt + (size_t)(n0 + r) * DIM + k0 + c8, &Bs[(i * 256 + w * 64) * 8]);
        }
        __syncthreads();
        bf16x8 af[4], bfr[4];
#pragma unroll
        for (int r = 0; r < 4; r++)
            af[r] = *(const bf16x8*)&As[(wr * 64 + r * 16 + l15) * 32 + lg * 8];
#pragma unroll
        for (int c = 0; c < 4; c++)
            bfr[c] = *(const bf16x8*)&Bs[(wc * 64 + c * 16 + l15) * 32 + lg * 8];
#pragma unroll
        for (int r = 0; r < 4; r++)
#pragma unroll
            for (int c = 0; c < 4; c++)
                acc[r][c] = MFMA16(af[r], bfr[c], acc[r][c]);
    }

    const int nloc = n0 + wc * 64;
    const bool even = (l15 & 1) == 0;
#pragma unroll
    for (int rt = 0; rt < 4; rt++) {
#pragma unroll
        for (int ct = 0; ct < 4; ct++) {
            const int c = ct * 16 + l15;
            const float bsv = bias[nloc + c];
            if (mode == 2) {
                // write V transposed: vT[(b*NKV+kh)*64 + d][t], 4 consecutive t packed
                const int col = nloc + c;               // 0..255
                const int khh = col >> 6, d = col & 63;
                const int bb = m0 >> 11;
                const int t = (m0 & (SEQ - 1)) + wr * 64 + rt * 16 + lg * 4;
                float v0 = acc[rt][ct][0] + bsv;
                float v1 = acc[rt][ct][1] + bsv;
                float v2 = acc[rt][ct][2] + bsv;
                float v3 = acc[rt][ct][3] + bsv;
                unsigned short* dst = vT + ((size_t)(bb * NKV + khh) * 64 + d) * SEQ + t;
                *(uint2*)dst = make_uint2(pack2bf(v0, v1), pack2bf(v2, v3));
            } else {
                const int p = c >> 1;
#pragma unroll
                for (int q = 0; q < 4; q++) {
                    const int mrow = m0 + wr * 64 + rt * 16 + lg * 4 + q;
                    float val = acc[rt][ct][q] + bsv;
                    float prt = __shfl_xor(val, 1);
                    const int t = mrow & (SEQ - 1);
                    float cs = cosb[t * HALF + p];
                    float sn = sinb[t * HALF + p];
                    float outv = even ? (val * cs - prt * sn) : (prt * sn - val * cs);
                    int outc = even ? p : (p + 32);
                    if (mode == 0) qbuf[(size_t)mrow * DIM + nloc + outc] = f2bf(outv * QSCALE);
                    else           kbuf[(size_t)mrow * KVD + nloc + outc] = f2bf(outv);
                }
            }
        }
    }
}

// ---------------- flash attention, paired q-tiles (x, 31-x) for load balance ----------------
__global__ __launch_bounds__(256) void attn_mfma_kernel(
    const unsigned short* __restrict__ qb, const unsigned short* __restrict__ kb,
    const unsigned short* __restrict__ vT, unsigned short* __restrict__ ctx)
{
    __shared__ unsigned short Qs[64 * 64];   // [q][d], d XOR-swizzled by (q&7)<<3
    __shared__ unsigned short Ks[64 * 64];   // [key][d], same swizzle
    __shared__ unsigned short Vt[64 * 64];   // [d][j], j swizzled by (d&7)<<3
    __shared__ unsigned Pw[4][16 * 32];      // per-wave P rows

    const int tid = threadIdx.x;
    const int lane = tid & 63, w = tid >> 6;
    const int l15 = lane & 15, lg = lane >> 4;
    const int xpair = blockIdx.x;            // 0..15
    const int h = blockIdx.y;
    const int b = blockIdx.z;
    const int kh = h >> 2;

    const unsigned short* qg = qb + (size_t)b * SEQ * DIM + (size_t)h * HD;
    const unsigned short* kg = kb + (size_t)b * SEQ * KVD + (size_t)kh * HD;
    const unsigned short* vg = vT + ((size_t)(b * NKV + kh) * HD) * SEQ;

    const int qg_row = w * 16 + l15;
    const int swzd = (l15 & 7) << 3;
    unsigned* PW = &Pw[w][l15 * 32];
    const int pswz = (l15 & 7) << 2;

#pragma unroll 1
    for (int p = 0; p < 2; p++) {
        const int xt = (p == 0) ? xpair : (31 - xpair);
        const int q0 = xt * 64;

        // ---- stage Q for this half (pre-swizzled global source, linear LDS dest) ----
#pragma unroll
        for (int i = 0; i < 2; i++) {
            int S = i * 256 + w * 64 + lane;
            int r = S >> 3, qd = S & 7;
            gll16(qg + (size_t)(q0 + r) * DIM + ((qd ^ (r & 7)) * 8),
                  &Qs[(i * 256 + w * 64) * 8]);
        }

        f32x4 o[4];
#pragma unroll
        for (int i = 0; i < 4; i++) o[i] = (f32x4){0.f, 0.f, 0.f, 0.f};
        float mrun = -INFINITY, lrun = 0.f;
        bf16x8 bq0 = {}, bq1 = {};

        const int nch = xt + 1;
#pragma unroll 1
        for (int ch = 0; ch < nch; ch++) {
            const int kv0 = ch * 64;
            __syncthreads();                   // waves done with previous Ks/Vt
#pragma unroll
            for (int i = 0; i < 2; i++) {
                int S = i * 256 + w * 64 + lane;
                int r = S >> 3, qd = S & 7;
                gll16(kg + (size_t)(kv0 + r) * KVD + ((qd ^ (r & 7)) * 8),
                      &Ks[(i * 256 + w * 64) * 8]);
                gll16(vg + (size_t)r * SEQ + kv0 + ((qd ^ (r & 7)) * 8),
                      &Vt[(i * 256 + w * 64) * 8]);
            }
            __syncthreads();                   // staging complete

            if (ch == 0) {
                bq0 = *(const bf16x8*)&Qs[qg_row * 64 + ((lg * 8) ^ swzd)];
                bq1 = *(const bf16x8*)&Qs[qg_row * 64 + ((32 + lg * 8) ^ swzd)];
            }

            // ---- S^T = K Q^T : lane holds S[q=l15][key = ct*16 + lg*4 + reg] ----
            f32x4 sacc[4];
#pragma unroll
            for (int i = 0; i < 4; i++) sacc[i] = (f32x4){0.f, 0.f, 0.f, 0.f};
#pragma unroll
            for (int ct = 0; ct < 4; ct++) {
                const int kr = ct * 16 + l15;
                bf16x8 ak = *(const bf16x8*)&Ks[kr * 64 + ((lg * 8) ^ swzd)];
                sacc[ct] = MFMA16(ak, bq0, sacc[ct]);
            }
#pragma unroll
            for (int ct = 0; ct < 4; ct++) {
                const int kr = ct * 16 + l15;
                bf16x8 ak = *(const bf16x8*)&Ks[kr * 64 + ((32 + lg * 8) ^ swzd)];
                sacc[ct] = MFMA16(ak, bq1, sacc[ct]);
            }

            // ---- mask + in-register max (S already in exp2 domain via QSCALE) ----
            const bool diag = (kv0 == q0);
            float mx = -INFINITY;
#pragma unroll
            for (int ct = 0; ct < 4; ct++) {
#pragma unroll
                for (int r = 0; r < 4; r++) {
                    float sv = sacc[ct][r];
                    if (diag && (ct * 16 + lg * 4 + r > qg_row)) sv = -INFINITY;
                    sacc[ct][r] = sv;
                    mx = fmaxf(mx, sv);
                }
            }
            mx = fmaxf(mx, __shfl_xor(mx, 16));
            mx = fmaxf(mx, __shfl_xor(mx, 32));

            float al = 1.0f;
            if (!__all(mx <= mrun + 8.0f)) {   // T13 defer-max (log2 units)
                float mnew = fmaxf(mrun, mx);
                al = exp2f(mrun - mnew);
                mrun = mnew;
                float alb0 = __shfl(al, lg * 4 + 0);
                float alb1 = __shfl(al, lg * 4 + 1);
                float alb2 = __shfl(al, lg * 4 + 2);
                float alb3 = __shfl(al, lg * 4 + 3);
#pragma unroll
                for (int dt = 0; dt < 4; dt++) {
                    o[dt][0] *= alb0; o[dt][1] *= alb1;
                    o[dt][2] *= alb2; o[dt][3] *= alb3;
                }
            }

            // ---- P = exp2(S - mrun), row-sum, pack ----
            float rs = 0.f;
            unsigned pk0[4], pk1[4];
#pragma unroll
            for (int ct = 0; ct < 4; ct++) {
                float p0 = exp2f(sacc[ct][0] - mrun);
                float p1 = exp2f(sacc[ct][1] - mrun);
                float p2 = exp2f(sacc[ct][2] - mrun);
                float p3 = exp2f(sacc[ct][3] - mrun);
                rs += (p0 + p1) + (p2 + p3);
                pk0[ct] = pack2bf(p0, p1);
                pk1[ct] = pack2bf(p2, p3);
            }
            rs += __shfl_xor(rs, 16);
            rs += __shfl_xor(rs, 32);
            lrun = lrun * al + rs;

            // ---- P rows -> per-wave LDS (packed b64, swizzled) ----
#pragma unroll
            for (int ct = 0; ct < 4; ct++) {
                int wrd = (ct * 8 + lg * 2) ^ pswz;
                *(uint2*)&PW[wrd] = make_uint2(pk0[ct], pk1[ct]);
            }

            // ---- O += P V ----
#pragma unroll
            for (int s = 0; s < 2; s++) {
                int wrd = (s * 16 + lg * 4) ^ pswz;
                bf16x8 ap = *(const bf16x8*)&PW[wrd];
#pragma unroll
                for (int dt = 0; dt < 4; dt++) {
                    const int d = dt * 16 + l15;
                    bf16x8 bv2 = *(const bf16x8*)&Vt[d * 64 + ((s * 32 + lg * 8) ^ ((d & 7) << 3))];
                    o[dt] = MFMA16(ap, bv2, o[dt]);
                }
            }
        }

        // ---- normalize + write ctx ----
        float linv = 1.0f / lrun;
        float lb0 = __shfl(linv, lg * 4 + 0);
        float lb1 = __shfl(linv, lg * 4 + 1);
        float lb2 = __shfl(linv, lg * 4 + 2);
        float lb3 = __shfl(linv, lg * 4 + 3);
#pragma unroll
        for (int dt = 0; dt < 4; dt++) {
            const size_t base = (size_t)(b * SEQ + q0 + w * 16 + lg * 4) * DIM + h * HD + dt * 16 + l15;
            ctx[base]           = f2bf(o[dt][0] * lb0);
            ctx[base + DIM]     = f2bf(o[dt][1] * lb1);
            ctx[base + 2 * DIM] = f2bf(o[dt][2] * lb2);
            ctx[base + 3 * DIM] = f2bf(o[dt][3] * lb3);
        }
    }
}

// ---------------- out projection (bf16 MFMA, fp32 out) ----------------
__global__ __launch_bounds__(256) void outproj_kernel(
    const unsigned short* __restrict__ ctx, const unsigned short* __restrict__ wot,
    const float* __restrict__ bo, float* __restrict__ out)
{
    __shared__ unsigned short As[128 * 32];
    __shared__ unsigned short Bs[128 * 32];
    const int tid = threadIdx.x;
    const int lane = tid & 63, w = tid >> 6;
    const int l15 = lane & 15, lg = lane >> 4;
    const int m0 = blockIdx.y * 128;
    const int n0 = blockIdx.x * 128;
    const int wr = w >> 1, wc = w & 1;

    f32x4 acc[4][4];
#pragma unroll
    for (int i = 0; i < 4; i++)
#pragma unroll
        for (int j = 0; j < 4; j++) acc[i][j] = (f32x4){0.f, 0.f, 0.f, 0.f};

    for (int k0 = 0; k0 < DIM; k0 += 32) {
        __syncthreads();
#pragma unroll
        for (int i = 0; i < 2; i++) {
            int S = i * 256 + w * 64 + lane;
            int r = S >> 2, c8 = (S & 3) * 8;
            gll16(ctx + (size_t)(m0 + r) * DIM + k0 + c8, &As[(i * 256 + w * 64) * 8]);
            gll16(wot + (size_t)(n0 + r) * DIM + k0 + c8, &Bs[(i * 256 + w * 64) * 8]);
        }
        __syncthreads();
        bf16x8 af[4], bfr[4];
#pragma unroll
        for (int r = 0; r < 4; r++)
            af[r] = *(const bf16x8*)&As[(wr * 64 + r * 16 + l15) * 32 + lg * 8];
#pragma unroll
        for (int c = 0; c < 4; c++)
            bfr[c] = *(const bf16x8*)&Bs[(wc * 64 + c * 16 + l15) * 32 + lg * 8];
#pragma unroll
        for (int r = 0; r < 4; r++)
#pragma unroll
            for (int c = 0; c < 4; c++)
                acc[r][c] = MFMA16(af[r], bfr[c], acc[r][c]);
    }

#pragma unroll
    for (int rt = 0; rt < 4; rt++) {
#pragma unroll
        for (int ct = 0; ct < 4; ct++) {
            const int ncol = n0 + wc * 64 + ct * 16 + l15;
            const float bsv = bo[ncol];
#pragma unroll
            for (int q = 0; q < 4; q++) {
                const int mrow = m0 + wr * 64 + rt * 16 + lg * 4 + q;
                out[(size_t)mrow * DIM + ncol] = acc[rt][ct][q] + bsv;
            }
        }
    }
}

extern "C" void kernel_launch(void* const* d_in, const int* in_sizes, int n_in,
                              void* d_out, int out_size, void* d_ws, size_t ws_size,
                              hipStream_t stream) {
    (void)in_sizes; (void)n_in; (void)out_size; (void)ws_size;
    const float* x  = (const float*)d_in[0];
    const float* Wq = (const float*)d_in[1];
    const float* bq = (const float*)d_in[2];
    const float* Wk = (const float*)d_in[3];
    const float* bk = (const float*)d_in[4];
    const float* Wv = (const float*)d_in[5];
    const float* bv = (const float*)d_in[6];
    const float* Wo = (const float*)d_in[7];
    const float* bo = (const float*)d_in[8];
    float* out = (float*)d_out;
    char* ws = (char*)d_ws;

    unsigned short* xb  = (unsigned short*)(ws);              //  8 MB
    unsigned short* qbf = (unsigned short*)(ws + 8388608);    //  8 MB
    unsigned short* kbf = (unsigned short*)(ws + 16777216);   //  2 MB
    unsigned short* ctx = (unsigned short*)(ws + 20971520);   //  8 MB
    unsigned short* wqt = (unsigned short*)(ws + 29360128);   //  2 MB
    unsigned short* wkt = (unsigned short*)(ws + 31457280);   // .5 MB
    unsigned short* wvt = (unsigned short*)(ws + 31981568);   // .5 MB
    unsigned short* wot = (unsigned short*)(ws + 32505856);   //  2 MB
    float* cosb = (float*)(ws + 34603008);                    // .25 MB
    float* sinb = (float*)(ws + 34865152);                    // .25 MB
    unsigned short* vTb = (unsigned short*)(ws + 35127296);   //  4 MB  [8][64][2048]

    hipLaunchKernelGGL(prep_kernel, dim3(3328), dim3(256), 0, stream,
                       x, Wq, Wk, Wv, Wo, xb, wqt, wkt, wvt, wot, cosb, sinb);
    hipLaunchKernelGGL(qkv_gemm_kernel, dim3(12, 32), dim3(256), 0, stream,
                       xb, wqt, wkt, wvt, bq, bk, bv, cosb, sinb, qbf, kbf, vTb);
    hipLaunchKernelGGL(attn_mfma_kernel, dim3(16, NH, NB), dim3(256), 0, stream,
                       qbf, kbf, vTb, ctx);
    hipLaunchKernelGGL(outproj_kernel, dim3(8, 32), dim3(256), 0, stream,
                       ctx, wot, bo, out);
}